// Round 8
// baseline (420.038 us; speedup 1.0000x reference)
//
#include <hip/hip_runtime.h>
#include <math.h>

// ---------------------------------------------------------------------------
// HimNet multimode v8. B=8,N=1000,CIN=16,H=64,D=16,K=3,XIN=80,K*XIN=240,2H=128
// v7 with the glds staging fixed: swizzle applied to the GLOBAL source
// address (per-lane global addrs are allowed); LDS destination stays linear
// (global_load_lds is wave-uniform-base + lane*16 — no LDS scatter).
// All MFMA on 32x32x16 bf16; cheb 64x64 BK=128 dbuf; meta: A-frags in regs,
// B dbuf in 16KB k-halves, register d-fold; prep merged into one launch.
// ---------------------------------------------------------------------------

typedef __attribute__((ext_vector_type(8))) short s16x8;
typedef __attribute__((ext_vector_type(16))) float f32x16;
typedef unsigned short u16;
typedef unsigned int u32;
typedef unsigned long long u64;

__device__ __forceinline__ u32 f2bf(float f) {
  union { float f; u32 u; } v; v.f = f;
  return (v.u + 0x7FFFu + ((v.u >> 16) & 1u)) >> 16;  // RNE
}
__device__ __forceinline__ float bf2f(u16 h) {
  union { u32 u; float f; } v; v.u = (u32)h << 16; return v.f;
}
__device__ __forceinline__ void glds16(const u16* g, u16* l) {
  __builtin_amdgcn_global_load_lds(
      (const __attribute__((address_space(1))) void*)g,
      (__attribute__((address_space(3))) void*)l, 16, 0, 0);
}

// ---------------------------------------------------------------------------
// prep: S16, Xt, Ag kc0, K-pads, AgU x-part, n-pads, ewG, BiG, BiU, BtG, BtU
// ---------------------------------------------------------------------------
#define E0 3145728   // S16 3x1024x1024
#define E1 1966080   // Xt 3x640x1024
#define E2 1920000   // Ag kc0 cols 0..79
#define E3 384000    // Ag K-pad 240..255
#define E4 384000    // AgU x cols 0..15
#define E5 384000    // AgU K-pad
#define E6 119808    // n-pad rows of T1t/ZSt/SZ1t
#define E7 48000     // ewG 3x1000x16
#define E8 384000    // BiG 3x1000x128
#define E9 192000    // BiU 3x1000x64
#define E10 786432   // BtG 2048x256 + BtU 1024x256
// total = 9714048 -> 37946 blocks

struct PrepArgs {
  const float* x[3]; const float* st[3]; const float* S[3]; const float* emb[3];
  const float *me, *Bg, *Bu, *Wg, *Wu;
  u16 *S16, *Xt, *Ag, *AgU, *T1t, *ZSt, *SZ1t, *BtG, *BtU;
  float *ewG, *BiG, *BiU;
};

__global__ void prep(PrepArgs P) {
  long idx = (long)blockIdx.x * 256 + threadIdx.x;
  if (idx < E0) {
    int m = (int)(idx >> 20); int rem = (int)(idx & 1048575);
    int n = rem >> 10, k = rem & 1023;
    float v = (n < 1000 && k < 1000) ? P.S[m][n * 1000 + k] : 0.f;
    P.S16[(size_t)m * 1048576 + rem] = (u16)f2bf(v); return;
  }
  idx -= E0;
  if (idx < E1) {
    int m = (int)(idx / 655360); int rem = (int)(idx % 655360);
    int col = rem >> 10, nn = rem & 1023;
    int b = col / 80, c = col % 80;
    float v = 0.f;
    if (nn < 1000) v = (c < 16) ? P.x[m][(b * 1000 + nn) * 16 + c]
                                : P.st[m][(b * 1000 + nn) * 64 + c - 16];
    P.Xt[(size_t)m * 655360 + rem] = (u16)f2bf(v); return;
  }
  idx -= E1;
  if (idx < E2) {
    int m = (int)(idx / 640000); int rem = (int)(idx % 640000);
    int r = rem / 80, c = rem % 80;
    int n = r >> 3, b = r & 7;
    float v = (c < 16) ? P.x[m][(b * 1000 + n) * 16 + c]
                       : P.st[m][(b * 1000 + n) * 64 + c - 16];
    P.Ag[(size_t)m * 2048000 + (size_t)r * 256 + c] = (u16)f2bf(v); return;
  }
  idx -= E2;
  if (idx < E3) {
    int m = (int)(idx / 128000); int rem = (int)(idx % 128000);
    int r = rem / 16, c = 240 + rem % 16;
    P.Ag[(size_t)m * 2048000 + (size_t)r * 256 + c] = 0; return;
  }
  idx -= E3;
  if (idx < E4) {
    int m = (int)(idx / 128000); int rem = (int)(idx % 128000);
    int r = rem / 16, c = rem % 16;
    int n = r >> 3, b = r & 7;
    P.AgU[(size_t)m * 2048000 + (size_t)r * 256 + c] =
        (u16)f2bf(P.x[m][(b * 1000 + n) * 16 + c]); return;
  }
  idx -= E4;
  if (idx < E5) {
    int m = (int)(idx / 128000); int rem = (int)(idx % 128000);
    int r = rem / 16, c = 240 + rem % 16;
    P.AgU[(size_t)m * 2048000 + (size_t)r * 256 + c] = 0; return;
  }
  idx -= E5;
  if (idx < E6) {
    int m = (int)(idx / 39936); int rem = (int)(idx % 39936);
    if (rem < 15360) { int col = rem / 24, j = rem % 24;
      P.T1t[(size_t)m * 655360 + col * 1024 + 1000 + j] = 0; }
    else if (rem < 27648) { int e = rem - 15360; int col = e / 24, j = e % 24;
      P.ZSt[(size_t)m * 524288 + col * 1024 + 1000 + j] = 0; }
    else { int e = rem - 27648; int col = e / 24, j = e % 24;
      P.SZ1t[(size_t)m * 524288 + col * 1024 + 1000 + j] = 0; }
    return;
  }
  idx -= E6;
  if (idx < E7) {  // ewG[m][n][d]
    int m = (int)(idx / 16000); int rem = (int)(idx % 16000);
    int n = rem >> 4, d = rem & 15;
    P.ewG[idx] = P.emb[m][n * 16 + d] * P.me[m * 16 + d]; return;
  }
  idx -= E7;
  if (idx < E8) {  // BiG
    int m = (int)(idx / 128000); int rem = (int)(idx % 128000);
    int n = rem >> 7, o = rem & 127;
    float s = 0.f;
#pragma unroll
    for (int d = 0; d < 16; ++d)
      s += P.emb[m][n * 16 + d] * P.me[m * 16 + d] * P.Bg[d * 128 + o];
    P.BiG[idx] = s; return;
  }
  idx -= E8;
  if (idx < E9) {  // BiU
    int m = (int)(idx / 64000); int rem = (int)(idx % 64000);
    int n = rem >> 6, o = rem & 63;
    float s = 0.f;
#pragma unroll
    for (int d = 0; d < 16; ++d)
      s += P.emb[m][n * 16 + d] * P.me[m * 16 + d] * P.Bu[d * 64 + o];
    P.BiU[idx] = s; return;
  }
  idx -= E9;
  if (idx < E10) {  // packW d-major
    if (idx < 2048 * 256) {
      int col = (int)(idx >> 8), k = (int)(idx & 255);
      int d = col >> 7, o = col & 127;
      P.BtG[idx] = (k < 240) ? (u16)f2bf(P.Wg[d * 30720 + k * 128 + o]) : (u16)0;
    } else {
      long i2 = idx - 2048 * 256;
      int col = (int)(i2 >> 8), k = (int)(i2 & 255);
      int d = col >> 6, o = col & 63;
      P.BtU[i2] = (k < 240) ? (u16)f2bf(P.Wu[d * 15360 + k * 64 + o]) : (u16)0;
    }
    return;
  }
}

// ---------------------------------------------------------------------------
// cheb_v8: D[f][n] = alpha*sum_k A[f][k]*S16[n][k] (+beta*Res[f][n])
// 64f x 64n tile, BK=128 (8 iters), dbuf glds, 32x32x16 MFMA.
// Staging: global chunk (c ^ (r&15)) -> linear LDS slot c (lane*16 rule).
// Read: global chunk q of row r is at slot q ^ (r&15).
// 4 waves 2x2: wave = 32f x 32n. flags: 1=hasRes, 2=hasY, 4=hasAgX
// ---------------------------------------------------------------------------
struct ChebArgs {
  const u16* S16[3]; const u16* A[3]; const u16* Res[3];
  u16* Yt[3]; u16* AgA[3]; u16* AgX[3];
};

__global__ __launch_bounds__(256, 2) void cheb_v8(ChebArgs g, int fdiv, int agbase,
                                                  float alpha, float beta, int flags) {
  const int mode = blockIdx.z;
  const u16* __restrict__ Ab = g.A[mode];
  const u16* __restrict__ Sb = g.S16[mode];

  __shared__ u16 As[2][64 * 128];   // 2 x 16 KB
  __shared__ u16 Bs[2][64 * 128];   // 2 x 16 KB

  const int t = threadIdx.x, lane = t & 63, wid = t >> 6;
  const int rowg = wid >> 1, colg = wid & 1;
  const int l31 = lane & 31, l5 = lane >> 5;
  const int row0 = blockIdx.y * 64, n0 = blockIdx.x * 64;

#define CSTAGE(kk, bb)                                                           \
  {                                                                              \
    _Pragma("unroll")                                                            \
    for (int p = 0; p < 4; ++p) {                                                \
      int idx = p * 256 + t; int r = idx >> 4, c = idx & 15, cg = c ^ (r & 15);  \
      glds16(Ab + (size_t)(row0 + r) * 1024 + (kk) + cg * 8, &As[bb][idx * 8]);  \
    }                                                                            \
    _Pragma("unroll")                                                            \
    for (int p = 0; p < 4; ++p) {                                                \
      int idx = p * 256 + t; int r = idx >> 4, c = idx & 15, cg = c ^ (r & 15);  \
      glds16(Sb + (size_t)(n0 + r) * 1024 + (kk) + cg * 8, &Bs[bb][idx * 8]);    \
    }                                                                            \
  }

  f32x16 acc;
#pragma unroll
  for (int i = 0; i < 16; ++i) acc[i] = 0.f;

  const int ar = rowg * 32 + l31;   // A row in tile
  const int br = colg * 32 + l31;   // B row in tile

  CSTAGE(0, 0);
  for (int it = 0; it < 8; ++it) {
    __syncthreads();                        // drain glds(it), protect buf reuse
    if (it < 7) CSTAGE((it + 1) * 128, (it + 1) & 1);
    const u16* Ac = As[it & 1];
    const u16* Bc = Bs[it & 1];
#pragma unroll
    for (int ki = 0; ki < 8; ++ki) {
      int q = ki * 2 + l5;
      s16x8 a = *(const s16x8*)&Ac[ar * 128 + (q ^ (ar & 15)) * 8];
      s16x8 b = *(const s16x8*)&Bc[br * 128 + (q ^ (br & 15)) * 8];
      acc = __builtin_amdgcn_mfma_f32_32x32x16_bf16(a, b, acc, 0, 0, 0);
    }
  }

  // epilogue: C/D 32x32 layout: col=lane&31, row=(reg&3)+8*(reg>>2)+4*(lane>>5)
  int n = n0 + br;
  if (n < 1000) {
#pragma unroll
    for (int rg = 0; rg < 4; ++rg) {
      int f0 = row0 + rowg * 32 + 8 * rg + 4 * l5;
      int b = f0 / fdiv, c0 = f0 - b * fdiv;
      u16 pk[4];
#pragma unroll
      for (int j = 0; j < 4; ++j) {
        float v = alpha * acc[rg * 4 + j];
        if (flags & 1) v += beta * bf2f(g.Res[mode][(size_t)(f0 + j) * 1024 + n]);
        u16 h = (u16)f2bf(v);
        pk[j] = h;
        if (flags & 2) g.Yt[mode][(size_t)(f0 + j) * 1024 + n] = h;
      }
      u64 pv = (u64)pk[0] | ((u64)pk[1] << 16) | ((u64)pk[2] << 32) | ((u64)pk[3] << 48);
      *(u64*)&g.AgA[mode][(size_t)(n * 8 + b) * 256 + agbase + c0] = pv;
      if ((flags & 4) && c0 < 16)
        *(u64*)&g.AgX[mode][(size_t)(n * 8 + b) * 256 + agbase + c0] = pv;
    }
  }
}

// ---------------------------------------------------------------------------
// meta8: out[r,o] = act( sum_d ewG[n,d]*(A[r,:].Btd[d*O+o,:]) + bias[n,o] )
// Block 64 rows x 64 o-cols (gate col-split via grid.x); wave 32x32.
// A frags one-time global->regs (64 VGPR); B staged in 16KB k-halves dbuf
// (global-side swizzle, linear LDS). 32 stage-iters, 1 barrier each;
// register d-fold (node = rowg*4 + (reg>>2)).
// ---------------------------------------------------------------------------
struct MetaArgs {
  const u16* Ag;        // [3][8000][256]
  const u16* Bt;        // [O*16][256] d-major
  const float* ewG;     // [3][1000][16]
  const float* Bias;    // [3][1000][O]
  const float* state[3];
  u16* ZSt;             // [3][512][1024]
  u16* AgU;             // [3][8000][256]
  float* Rb;            // [3][8000][64]
  float* out;
};

__global__ __launch_bounds__(256, 3) void meta8(MetaArgs A, int is_gate, int O) {
  const int mode = blockIdx.z;
  const int row0 = blockIdx.y * 64;
  const int ocb = blockIdx.x * 64;

  __shared__ u16 Bs[2][64 * 128];   // 2 x 16 KB
  __shared__ float ewS[8][17];

  const int t = threadIdx.x, lane = t & 63, wid = t >> 6;
  const int rowg = wid >> 1, colg = wid & 1;
  const int l31 = lane & 31, l5 = lane >> 5;

  if (t < 128)
    ewS[t >> 4][t & 15] = A.ewG[(size_t)mode * 16000 + (row0 >> 3) * 16 + t];

  const u16* Agm = A.Ag + (size_t)mode * 2048000;
  const u16* arow = Agm + (size_t)(row0 + rowg * 32 + l31) * 256 + l5 * 8;
  s16x8 afr[16];
#pragma unroll
  for (int ki = 0; ki < 16; ++ki) afr[ki] = *(const s16x8*)(arow + ki * 16);

#define MSTAGE(it, bb)                                                           \
  {                                                                              \
    int d_ = (it) >> 1, kh_ = (it) & 1;                                          \
    int brow = d_ * O + ocb;                                                     \
    _Pragma("unroll")                                                            \
    for (int p = 0; p < 4; ++p) {                                                \
      int idx = p * 256 + t; int r = idx >> 4, c = idx & 15, cg = c ^ (r & 15);  \
      glds16(A.Bt + (size_t)(brow + r) * 256 + kh_ * 128 + cg * 8,               \
             &Bs[bb][idx * 8]);                                                  \
    }                                                                            \
  }

  f32x16 outacc, acc;
#pragma unroll
  for (int i = 0; i < 16; ++i) outacc[i] = 0.f;

  const int br = colg * 32 + l31;
  MSTAGE(0, 0);
  for (int it = 0; it < 32; ++it) {
    __syncthreads();
    if (it < 31) MSTAGE(it + 1, (it + 1) & 1);
    const u16* Bc = Bs[it & 1];
    const int kh = it & 1;
    if (kh == 0) {
#pragma unroll
      for (int i = 0; i < 16; ++i) acc[i] = 0.f;
    }
#pragma unroll
    for (int ki = 0; ki < 8; ++ki) {
      int q = ki * 2 + l5;
      s16x8 b = *(const s16x8*)&Bc[br * 128 + (q ^ (br & 15)) * 8];
      acc = __builtin_amdgcn_mfma_f32_32x32x16_bf16(afr[kh * 8 + ki], b, acc, 0, 0, 0);
    }
    if (kh == 1) {
      const int d = it >> 1;
#pragma unroll
      for (int reg = 0; reg < 16; ++reg)
        outacc[reg] += ewS[rowg * 4 + (reg >> 2)][d] * acc[reg];
    }
  }

  // epilogue
  const int o = ocb + br;
  const float* st = A.state[mode];
#pragma unroll
  for (int rg = 0; rg < 4; ++rg) {
#pragma unroll
    for (int j = 0; j < 4; ++j) {
      int r = row0 + rowg * 32 + 8 * rg + 4 * l5 + j;
      int n = r >> 3, bb = r & 7;
      float pre = outacc[rg * 4 + j] + A.Bias[(size_t)mode * 1000 * O + n * O + o];
      if (is_gate) {
        float sg = 1.f / (1.f + __expf(-pre));
        if (o < 64) {
          float zs = sg * st[(bb * 1000 + n) * 64 + o];
          A.ZSt[(size_t)mode * 524288 + (size_t)(bb * 64 + o) * 1024 + n] = (u16)f2bf(zs);
          A.AgU[(size_t)mode * 2048000 + (size_t)r * 256 + 16 + o] = (u16)f2bf(zs);
        } else {
          A.Rb[(size_t)mode * 512000 + r * 64 + (o - 64)] = sg;
        }
      } else {
        float hc = tanhf(pre);
        float rr = A.Rb[(size_t)mode * 512000 + r * 64 + o];
        float s2 = st[(bb * 1000 + n) * 64 + o];
        A.out[(size_t)mode * 512000 + (bb * 1000 + n) * 64 + o] = rr * s2 + (1.f - rr) * hc;
      }
    }
  }
}

// ---------------------------------------------------------------------------
extern "C" void kernel_launch(void* const* d_in, const int* in_sizes, int n_in,
                              void* d_out, int out_size, void* d_ws, size_t ws_size,
                              hipStream_t stream) {
  const float* x[3]   = {(const float*)d_in[0], (const float*)d_in[1], (const float*)d_in[2]};
  const float* st[3]  = {(const float*)d_in[3], (const float*)d_in[4], (const float*)d_in[5]};
  const float* S[3]   = {(const float*)d_in[6], (const float*)d_in[7], (const float*)d_in[8]};
  const float* emb[3] = {(const float*)d_in[9], (const float*)d_in[10], (const float*)d_in[11]};
  const float* me = (const float*)d_in[12];
  const float* Wg = (const float*)d_in[13];
  const float* Bg = (const float*)d_in[14];
  const float* Wu = (const float*)d_in[15];
  const float* Bu = (const float*)d_in[16];
  float* out = (float*)d_out;

  float* BiG = (float*)d_ws;            // 3*1000*128
  float* BiU = BiG + 384000;            // 3*1000*64
  float* Rb  = BiU + 192000;            // 3*8000*64
  float* ewG = Rb + 1536000;            // 3*1000*16
  u16* S16 = (u16*)(ewG + 48000);       // 3*1024*1024
  u16* Xt  = S16 + 3145728;             // 3*640*1024
  u16* T1t = Xt + 1966080;              // 3*640*1024
  u16* ZSt = T1t + 1966080;             // 3*512*1024
  u16* SZ1t= ZSt + 1572864;             // 3*512*1024
  u16* Ag  = SZ1t + 1572864;            // 3*8000*256
  u16* AgU = Ag + 6144000;              // 3*8000*256
  u16* BtG = AgU + 6144000;             // 2048*256
  u16* BtU = BtG + 524288;              // 1024*256

  {
    PrepArgs P;
    for (int m = 0; m < 3; ++m) {
      P.x[m] = x[m]; P.st[m] = st[m]; P.S[m] = S[m]; P.emb[m] = emb[m];
    }
    P.me = me; P.Bg = Bg; P.Bu = Bu; P.Wg = Wg; P.Wu = Wu;
    P.S16 = S16; P.Xt = Xt; P.Ag = Ag; P.AgU = AgU; P.T1t = T1t;
    P.ZSt = ZSt; P.SZ1t = SZ1t; P.BtG = BtG; P.BtU = BtU;
    P.ewG = ewG; P.BiG = BiG; P.BiU = BiU;
    prep<<<37946, 256, 0, stream>>>(P);
  }

  // cheb1: T1t = Xt @ S^T -> T1t + Ag[80..159] (+AgU x-part 80..95)
  {
    ChebArgs a;
    for (int m = 0; m < 3; ++m) {
      a.S16[m] = S16 + (size_t)m * 1048576; a.A[m] = Xt + (size_t)m * 655360;
      a.Res[m] = nullptr; a.Yt[m] = T1t + (size_t)m * 655360;
      a.AgA[m] = Ag + (size_t)m * 2048000; a.AgX[m] = AgU + (size_t)m * 2048000;
    }
    cheb_v8<<<dim3(16, 10, 3), 256, 0, stream>>>(a, 80, 80, 1.f, 0.f, 2 | 4);
  }
  // cheb2: T2t = 2*T1t @ S^T - Xt -> Ag[160..239] (+AgU x-part 160..175)
  {
    ChebArgs a;
    for (int m = 0; m < 3; ++m) {
      a.S16[m] = S16 + (size_t)m * 1048576; a.A[m] = T1t + (size_t)m * 655360;
      a.Res[m] = Xt + (size_t)m * 655360; a.Yt[m] = nullptr;
      a.AgA[m] = Ag + (size_t)m * 2048000; a.AgX[m] = AgU + (size_t)m * 2048000;
    }
    cheb_v8<<<dim3(16, 10, 3), 256, 0, stream>>>(a, 80, 160, 2.f, -1.f, 1 | 4);
  }
  // gate meta: reads Ag; writes ZSt + AgU[16..79] + Rb
  {
    MetaArgs a;
    a.Ag = Ag; a.Bt = BtG; a.ewG = ewG; a.Bias = BiG;
    a.ZSt = ZSt; a.AgU = AgU; a.Rb = Rb; a.out = out;
    for (int m = 0; m < 3; ++m) a.state[m] = st[m];
    meta8<<<dim3(2, 125, 3), 256, 0, stream>>>(a, 1, 128);
  }
  // cheb3: SZ1t = ZSt @ S^T -> SZ1t + AgU[96..159]
  {
    ChebArgs a;
    for (int m = 0; m < 3; ++m) {
      a.S16[m] = S16 + (size_t)m * 1048576; a.A[m] = ZSt + (size_t)m * 524288;
      a.Res[m] = nullptr; a.Yt[m] = SZ1t + (size_t)m * 524288;
      a.AgA[m] = AgU + (size_t)m * 2048000; a.AgX[m] = nullptr;
    }
    cheb_v8<<<dim3(16, 8, 3), 256, 0, stream>>>(a, 64, 96, 1.f, 0.f, 2);
  }
  // cheb4: SZ2t = 2*SZ1t @ S^T - ZSt -> AgU[176..239]
  {
    ChebArgs a;
    for (int m = 0; m < 3; ++m) {
      a.S16[m] = S16 + (size_t)m * 1048576; a.A[m] = SZ1t + (size_t)m * 524288;
      a.Res[m] = ZSt + (size_t)m * 524288; a.Yt[m] = nullptr;
      a.AgA[m] = AgU + (size_t)m * 2048000; a.AgX[m] = nullptr;
    }
    cheb_v8<<<dim3(16, 8, 3), 256, 0, stream>>>(a, 64, 176, 2.f, -1.f, 1);
  }
  // update meta: reads AgU; writes out
  {
    MetaArgs a;
    a.Ag = AgU; a.Bt = BtU; a.ewG = ewG; a.Bias = BiU;
    a.ZSt = ZSt; a.AgU = AgU; a.Rb = Rb; a.out = out;
    for (int m = 0; m < 3; ++m) a.state[m] = st[m];
    meta8<<<dim3(1, 125, 3), 256, 0, stream>>>(a, 0, 64);
  }
}

// Round 9
// 419.137 us; speedup vs baseline: 1.0022x; 1.0022x over previous
//
#include <hip/hip_runtime.h>
#include <math.h>

// ---------------------------------------------------------------------------
// HimNet multimode v9. B=8,N=1000,CIN=16,H=64,D=16,K=3,XIN=80,K*XIN=240,2H=128
// v8 with meta __launch_bounds__(256,2): the (256,3) cap (VGPR=52) demoted the
// 64-VGPR A-fragment array to per-tile global reloads -> 380MB HBM overfetch.
// (256,2) keeps afr resident (R6's meta5 proved 96+ VGPR stays resident).
// All MFMA on 32x32x16 bf16; cheb 64x64 BK=128 dbuf; meta: A-frags in regs,
// B dbuf in 16KB k-halves, register d-fold; prep merged into one launch.
// ---------------------------------------------------------------------------

typedef __attribute__((ext_vector_type(8))) short s16x8;
typedef __attribute__((ext_vector_type(16))) float f32x16;
typedef unsigned short u16;
typedef unsigned int u32;
typedef unsigned long long u64;

__device__ __forceinline__ u32 f2bf(float f) {
  union { float f; u32 u; } v; v.f = f;
  return (v.u + 0x7FFFu + ((v.u >> 16) & 1u)) >> 16;  // RNE
}
__device__ __forceinline__ float bf2f(u16 h) {
  union { u32 u; float f; } v; v.u = (u32)h << 16; return v.f;
}
__device__ __forceinline__ void glds16(const u16* g, u16* l) {
  __builtin_amdgcn_global_load_lds(
      (const __attribute__((address_space(1))) void*)g,
      (__attribute__((address_space(3))) void*)l, 16, 0, 0);
}

// ---------------------------------------------------------------------------
// prep: S16, Xt, Ag kc0, K-pads, AgU x-part, n-pads, ewG, BiG, BiU, BtG, BtU
// ---------------------------------------------------------------------------
#define E0 3145728   // S16 3x1024x1024
#define E1 1966080   // Xt 3x640x1024
#define E2 1920000   // Ag kc0 cols 0..79
#define E3 384000    // Ag K-pad 240..255
#define E4 384000    // AgU x cols 0..15
#define E5 384000    // AgU K-pad
#define E6 119808    // n-pad rows of T1t/ZSt/SZ1t
#define E7 48000     // ewG 3x1000x16
#define E8 384000    // BiG 3x1000x128
#define E9 192000    // BiU 3x1000x64
#define E10 786432   // BtG 2048x256 + BtU 1024x256
// total = 9714048 -> 37946 blocks

struct PrepArgs {
  const float* x[3]; const float* st[3]; const float* S[3]; const float* emb[3];
  const float *me, *Bg, *Bu, *Wg, *Wu;
  u16 *S16, *Xt, *Ag, *AgU, *T1t, *ZSt, *SZ1t, *BtG, *BtU;
  float *ewG, *BiG, *BiU;
};

__global__ void prep(PrepArgs P) {
  long idx = (long)blockIdx.x * 256 + threadIdx.x;
  if (idx < E0) {
    int m = (int)(idx >> 20); int rem = (int)(idx & 1048575);
    int n = rem >> 10, k = rem & 1023;
    float v = (n < 1000 && k < 1000) ? P.S[m][n * 1000 + k] : 0.f;
    P.S16[(size_t)m * 1048576 + rem] = (u16)f2bf(v); return;
  }
  idx -= E0;
  if (idx < E1) {
    int m = (int)(idx / 655360); int rem = (int)(idx % 655360);
    int col = rem >> 10, nn = rem & 1023;
    int b = col / 80, c = col % 80;
    float v = 0.f;
    if (nn < 1000) v = (c < 16) ? P.x[m][(b * 1000 + nn) * 16 + c]
                                : P.st[m][(b * 1000 + nn) * 64 + c - 16];
    P.Xt[(size_t)m * 655360 + rem] = (u16)f2bf(v); return;
  }
  idx -= E1;
  if (idx < E2) {
    int m = (int)(idx / 640000); int rem = (int)(idx % 640000);
    int r = rem / 80, c = rem % 80;
    int n = r >> 3, b = r & 7;
    float v = (c < 16) ? P.x[m][(b * 1000 + n) * 16 + c]
                       : P.st[m][(b * 1000 + n) * 64 + c - 16];
    P.Ag[(size_t)m * 2048000 + (size_t)r * 256 + c] = (u16)f2bf(v); return;
  }
  idx -= E2;
  if (idx < E3) {
    int m = (int)(idx / 128000); int rem = (int)(idx % 128000);
    int r = rem / 16, c = 240 + rem % 16;
    P.Ag[(size_t)m * 2048000 + (size_t)r * 256 + c] = 0; return;
  }
  idx -= E3;
  if (idx < E4) {
    int m = (int)(idx / 128000); int rem = (int)(idx % 128000);
    int r = rem / 16, c = rem % 16;
    int n = r >> 3, b = r & 7;
    P.AgU[(size_t)m * 2048000 + (size_t)r * 256 + c] =
        (u16)f2bf(P.x[m][(b * 1000 + n) * 16 + c]); return;
  }
  idx -= E4;
  if (idx < E5) {
    int m = (int)(idx / 128000); int rem = (int)(idx % 128000);
    int r = rem / 16, c = 240 + rem % 16;
    P.AgU[(size_t)m * 2048000 + (size_t)r * 256 + c] = 0; return;
  }
  idx -= E5;
  if (idx < E6) {
    int m = (int)(idx / 39936); int rem = (int)(idx % 39936);
    if (rem < 15360) { int col = rem / 24, j = rem % 24;
      P.T1t[(size_t)m * 655360 + col * 1024 + 1000 + j] = 0; }
    else if (rem < 27648) { int e = rem - 15360; int col = e / 24, j = e % 24;
      P.ZSt[(size_t)m * 524288 + col * 1024 + 1000 + j] = 0; }
    else { int e = rem - 27648; int col = e / 24, j = e % 24;
      P.SZ1t[(size_t)m * 524288 + col * 1024 + 1000 + j] = 0; }
    return;
  }
  idx -= E6;
  if (idx < E7) {  // ewG[m][n][d]
    int m = (int)(idx / 16000); int rem = (int)(idx % 16000);
    int n = rem >> 4, d = rem & 15;
    P.ewG[idx] = P.emb[m][n * 16 + d] * P.me[m * 16 + d]; return;
  }
  idx -= E7;
  if (idx < E8) {  // BiG
    int m = (int)(idx / 128000); int rem = (int)(idx % 128000);
    int n = rem >> 7, o = rem & 127;
    float s = 0.f;
#pragma unroll
    for (int d = 0; d < 16; ++d)
      s += P.emb[m][n * 16 + d] * P.me[m * 16 + d] * P.Bg[d * 128 + o];
    P.BiG[idx] = s; return;
  }
  idx -= E8;
  if (idx < E9) {  // BiU
    int m = (int)(idx / 64000); int rem = (int)(idx % 64000);
    int n = rem >> 6, o = rem & 63;
    float s = 0.f;
#pragma unroll
    for (int d = 0; d < 16; ++d)
      s += P.emb[m][n * 16 + d] * P.me[m * 16 + d] * P.Bu[d * 64 + o];
    P.BiU[idx] = s; return;
  }
  idx -= E9;
  if (idx < E10) {  // packW d-major
    if (idx < 2048 * 256) {
      int col = (int)(idx >> 8), k = (int)(idx & 255);
      int d = col >> 7, o = col & 127;
      P.BtG[idx] = (k < 240) ? (u16)f2bf(P.Wg[d * 30720 + k * 128 + o]) : (u16)0;
    } else {
      long i2 = idx - 2048 * 256;
      int col = (int)(i2 >> 8), k = (int)(i2 & 255);
      int d = col >> 6, o = col & 63;
      P.BtU[i2] = (k < 240) ? (u16)f2bf(P.Wu[d * 15360 + k * 64 + o]) : (u16)0;
    }
    return;
  }
}

// ---------------------------------------------------------------------------
// cheb_v8: D[f][n] = alpha*sum_k A[f][k]*S16[n][k] (+beta*Res[f][n])
// 64f x 64n tile, BK=128 (8 iters), dbuf glds, 32x32x16 MFMA.
// Staging: global chunk (c ^ (r&15)) -> linear LDS slot c (lane*16 rule).
// Read: global chunk q of row r is at slot q ^ (r&15).
// 4 waves 2x2: wave = 32f x 32n. flags: 1=hasRes, 2=hasY, 4=hasAgX
// ---------------------------------------------------------------------------
struct ChebArgs {
  const u16* S16[3]; const u16* A[3]; const u16* Res[3];
  u16* Yt[3]; u16* AgA[3]; u16* AgX[3];
};

__global__ __launch_bounds__(256, 2) void cheb_v8(ChebArgs g, int fdiv, int agbase,
                                                  float alpha, float beta, int flags) {
  const int mode = blockIdx.z;
  const u16* __restrict__ Ab = g.A[mode];
  const u16* __restrict__ Sb = g.S16[mode];

  __shared__ u16 As[2][64 * 128];   // 2 x 16 KB
  __shared__ u16 Bs[2][64 * 128];   // 2 x 16 KB

  const int t = threadIdx.x, lane = t & 63, wid = t >> 6;
  const int rowg = wid >> 1, colg = wid & 1;
  const int l31 = lane & 31, l5 = lane >> 5;
  const int row0 = blockIdx.y * 64, n0 = blockIdx.x * 64;

#define CSTAGE(kk, bb)                                                           \
  {                                                                              \
    _Pragma("unroll")                                                            \
    for (int p = 0; p < 4; ++p) {                                                \
      int idx = p * 256 + t; int r = idx >> 4, c = idx & 15, cg = c ^ (r & 15);  \
      glds16(Ab + (size_t)(row0 + r) * 1024 + (kk) + cg * 8, &As[bb][idx * 8]);  \
    }                                                                            \
    _Pragma("unroll")                                                            \
    for (int p = 0; p < 4; ++p) {                                                \
      int idx = p * 256 + t; int r = idx >> 4, c = idx & 15, cg = c ^ (r & 15);  \
      glds16(Sb + (size_t)(n0 + r) * 1024 + (kk) + cg * 8, &Bs[bb][idx * 8]);    \
    }                                                                            \
  }

  f32x16 acc;
#pragma unroll
  for (int i = 0; i < 16; ++i) acc[i] = 0.f;

  const int ar = rowg * 32 + l31;   // A row in tile
  const int br = colg * 32 + l31;   // B row in tile

  CSTAGE(0, 0);
  for (int it = 0; it < 8; ++it) {
    __syncthreads();                        // drain glds(it), protect buf reuse
    if (it < 7) CSTAGE((it + 1) * 128, (it + 1) & 1);
    const u16* Ac = As[it & 1];
    const u16* Bc = Bs[it & 1];
#pragma unroll
    for (int ki = 0; ki < 8; ++ki) {
      int q = ki * 2 + l5;
      s16x8 a = *(const s16x8*)&Ac[ar * 128 + (q ^ (ar & 15)) * 8];
      s16x8 b = *(const s16x8*)&Bc[br * 128 + (q ^ (br & 15)) * 8];
      acc = __builtin_amdgcn_mfma_f32_32x32x16_bf16(a, b, acc, 0, 0, 0);
    }
  }

  // epilogue: C/D 32x32 layout: col=lane&31, row=(reg&3)+8*(reg>>2)+4*(lane>>5)
  int n = n0 + br;
  if (n < 1000) {
#pragma unroll
    for (int rg = 0; rg < 4; ++rg) {
      int f0 = row0 + rowg * 32 + 8 * rg + 4 * l5;
      int b = f0 / fdiv, c0 = f0 - b * fdiv;
      u16 pk[4];
#pragma unroll
      for (int j = 0; j < 4; ++j) {
        float v = alpha * acc[rg * 4 + j];
        if (flags & 1) v += beta * bf2f(g.Res[mode][(size_t)(f0 + j) * 1024 + n]);
        u16 h = (u16)f2bf(v);
        pk[j] = h;
        if (flags & 2) g.Yt[mode][(size_t)(f0 + j) * 1024 + n] = h;
      }
      u64 pv = (u64)pk[0] | ((u64)pk[1] << 16) | ((u64)pk[2] << 32) | ((u64)pk[3] << 48);
      *(u64*)&g.AgA[mode][(size_t)(n * 8 + b) * 256 + agbase + c0] = pv;
      if ((flags & 4) && c0 < 16)
        *(u64*)&g.AgX[mode][(size_t)(n * 8 + b) * 256 + agbase + c0] = pv;
    }
  }
}

// ---------------------------------------------------------------------------
// meta9: out[r,o] = act( sum_d ewG[n,d]*(A[r,:].Btd[d*O+o,:]) + bias[n,o] )
// Block 64 rows x 64 o-cols (gate col-split via grid.x); wave 32x32.
// A frags one-time global->regs (64 VGPR, MUST stay resident -> bounds(256,2));
// B staged in 16KB k-halves dbuf (global-side swizzle, linear LDS).
// 32 stage-iters, 1 barrier each; register d-fold (node = rowg*4 + (reg>>2)).
// ---------------------------------------------------------------------------
struct MetaArgs {
  const u16* Ag;        // [3][8000][256]
  const u16* Bt;        // [O*16][256] d-major
  const float* ewG;     // [3][1000][16]
  const float* Bias;    // [3][1000][O]
  const float* state[3];
  u16* ZSt;             // [3][512][1024]
  u16* AgU;             // [3][8000][256]
  float* Rb;            // [3][8000][64]
  float* out;
};

__global__ __launch_bounds__(256, 2) void meta9(MetaArgs A, int is_gate, int O) {
  const int mode = blockIdx.z;
  const int row0 = blockIdx.y * 64;
  const int ocb = blockIdx.x * 64;

  __shared__ u16 Bs[2][64 * 128];   // 2 x 16 KB
  __shared__ float ewS[8][17];

  const int t = threadIdx.x, lane = t & 63, wid = t >> 6;
  const int rowg = wid >> 1, colg = wid & 1;
  const int l31 = lane & 31, l5 = lane >> 5;

  if (t < 128)
    ewS[t >> 4][t & 15] = A.ewG[(size_t)mode * 16000 + (row0 >> 3) * 16 + t];

  const u16* Agm = A.Ag + (size_t)mode * 2048000;
  const u16* arow = Agm + (size_t)(row0 + rowg * 32 + l31) * 256 + l5 * 8;
  s16x8 afr[16];
#pragma unroll
  for (int ki = 0; ki < 16; ++ki) afr[ki] = *(const s16x8*)(arow + ki * 16);

#define MSTAGE(it, bb)                                                           \
  {                                                                              \
    int d_ = (it) >> 1, kh_ = (it) & 1;                                          \
    int brow = d_ * O + ocb;                                                     \
    _Pragma("unroll")                                                            \
    for (int p = 0; p < 4; ++p) {                                                \
      int idx = p * 256 + t; int r = idx >> 4, c = idx & 15, cg = c ^ (r & 15);  \
      glds16(A.Bt + (size_t)(brow + r) * 256 + kh_ * 128 + cg * 8,               \
             &Bs[bb][idx * 8]);                                                  \
    }                                                                            \
  }

  f32x16 outacc, acc;
#pragma unroll
  for (int i = 0; i < 16; ++i) outacc[i] = 0.f;

  const int br = colg * 32 + l31;
  MSTAGE(0, 0);
  for (int it = 0; it < 32; ++it) {
    __syncthreads();
    if (it < 31) MSTAGE(it + 1, (it + 1) & 1);
    const u16* Bc = Bs[it & 1];
    const int kh = it & 1;
    if (kh == 0) {
#pragma unroll
      for (int i = 0; i < 16; ++i) acc[i] = 0.f;
    }
#pragma unroll
    for (int ki = 0; ki < 8; ++ki) {
      int q = ki * 2 + l5;
      s16x8 b = *(const s16x8*)&Bc[br * 128 + (q ^ (br & 15)) * 8];
      acc = __builtin_amdgcn_mfma_f32_32x32x16_bf16(afr[kh * 8 + ki], b, acc, 0, 0, 0);
    }
    if (kh == 1) {
      const int d = it >> 1;
#pragma unroll
      for (int reg = 0; reg < 16; ++reg)
        outacc[reg] += ewS[rowg * 4 + (reg >> 2)][d] * acc[reg];
    }
  }

  // epilogue
  const int o = ocb + br;
  const float* st = A.state[mode];
#pragma unroll
  for (int rg = 0; rg < 4; ++rg) {
#pragma unroll
    for (int j = 0; j < 4; ++j) {
      int r = row0 + rowg * 32 + 8 * rg + 4 * l5 + j;
      int n = r >> 3, bb = r & 7;
      float pre = outacc[rg * 4 + j] + A.Bias[(size_t)mode * 1000 * O + n * O + o];
      if (is_gate) {
        float sg = 1.f / (1.f + __expf(-pre));
        if (o < 64) {
          float zs = sg * st[(bb * 1000 + n) * 64 + o];
          A.ZSt[(size_t)mode * 524288 + (size_t)(bb * 64 + o) * 1024 + n] = (u16)f2bf(zs);
          A.AgU[(size_t)mode * 2048000 + (size_t)r * 256 + 16 + o] = (u16)f2bf(zs);
        } else {
          A.Rb[(size_t)mode * 512000 + r * 64 + (o - 64)] = sg;
        }
      } else {
        float hc = tanhf(pre);
        float rr = A.Rb[(size_t)mode * 512000 + r * 64 + o];
        float s2 = st[(bb * 1000 + n) * 64 + o];
        A.out[(size_t)mode * 512000 + (bb * 1000 + n) * 64 + o] = rr * s2 + (1.f - rr) * hc;
      }
    }
  }
}

// ---------------------------------------------------------------------------
extern "C" void kernel_launch(void* const* d_in, const int* in_sizes, int n_in,
                              void* d_out, int out_size, void* d_ws, size_t ws_size,
                              hipStream_t stream) {
  const float* x[3]   = {(const float*)d_in[0], (const float*)d_in[1], (const float*)d_in[2]};
  const float* st[3]  = {(const float*)d_in[3], (const float*)d_in[4], (const float*)d_in[5]};
  const float* S[3]   = {(const float*)d_in[6], (const float*)d_in[7], (const float*)d_in[8]};
  const float* emb[3] = {(const float*)d_in[9], (const float*)d_in[10], (const float*)d_in[11]};
  const float* me = (const float*)d_in[12];
  const float* Wg = (const float*)d_in[13];
  const float* Bg = (const float*)d_in[14];
  const float* Wu = (const float*)d_in[15];
  const float* Bu = (const float*)d_in[16];
  float* out = (float*)d_out;

  float* BiG = (float*)d_ws;            // 3*1000*128
  float* BiU = BiG + 384000;            // 3*1000*64
  float* Rb  = BiU + 192000;            // 3*8000*64
  float* ewG = Rb + 1536000;            // 3*1000*16
  u16* S16 = (u16*)(ewG + 48000);       // 3*1024*1024
  u16* Xt  = S16 + 3145728;             // 3*640*1024
  u16* T1t = Xt + 1966080;              // 3*640*1024
  u16* ZSt = T1t + 1966080;             // 3*512*1024
  u16* SZ1t= ZSt + 1572864;             // 3*512*1024
  u16* Ag  = SZ1t + 1572864;            // 3*8000*256
  u16* AgU = Ag + 6144000;              // 3*8000*256
  u16* BtG = AgU + 6144000;             // 2048*256
  u16* BtU = BtG + 524288;              // 1024*256

  {
    PrepArgs P;
    for (int m = 0; m < 3; ++m) {
      P.x[m] = x[m]; P.st[m] = st[m]; P.S[m] = S[m]; P.emb[m] = emb[m];
    }
    P.me = me; P.Bg = Bg; P.Bu = Bu; P.Wg = Wg; P.Wu = Wu;
    P.S16 = S16; P.Xt = Xt; P.Ag = Ag; P.AgU = AgU; P.T1t = T1t;
    P.ZSt = ZSt; P.SZ1t = SZ1t; P.BtG = BtG; P.BtU = BtU;
    P.ewG = ewG; P.BiG = BiG; P.BiU = BiU;
    prep<<<37946, 256, 0, stream>>>(P);
  }

  // cheb1: T1t = Xt @ S^T -> T1t + Ag[80..159] (+AgU x-part 80..95)
  {
    ChebArgs a;
    for (int m = 0; m < 3; ++m) {
      a.S16[m] = S16 + (size_t)m * 1048576; a.A[m] = Xt + (size_t)m * 655360;
      a.Res[m] = nullptr; a.Yt[m] = T1t + (size_t)m * 655360;
      a.AgA[m] = Ag + (size_t)m * 2048000; a.AgX[m] = AgU + (size_t)m * 2048000;
    }
    cheb_v8<<<dim3(16, 10, 3), 256, 0, stream>>>(a, 80, 80, 1.f, 0.f, 2 | 4);
  }
  // cheb2: T2t = 2*T1t @ S^T - Xt -> Ag[160..239] (+AgU x-part 160..175)
  {
    ChebArgs a;
    for (int m = 0; m < 3; ++m) {
      a.S16[m] = S16 + (size_t)m * 1048576; a.A[m] = T1t + (size_t)m * 655360;
      a.Res[m] = Xt + (size_t)m * 655360; a.Yt[m] = nullptr;
      a.AgA[m] = Ag + (size_t)m * 2048000; a.AgX[m] = AgU + (size_t)m * 2048000;
    }
    cheb_v8<<<dim3(16, 10, 3), 256, 0, stream>>>(a, 80, 160, 2.f, -1.f, 1 | 4);
  }
  // gate meta: reads Ag; writes ZSt + AgU[16..79] + Rb
  {
    MetaArgs a;
    a.Ag = Ag; a.Bt = BtG; a.ewG = ewG; a.Bias = BiG;
    a.ZSt = ZSt; a.AgU = AgU; a.Rb = Rb; a.out = out;
    for (int m = 0; m < 3; ++m) a.state[m] = st[m];
    meta9<<<dim3(2, 125, 3), 256, 0, stream>>>(a, 1, 128);
  }
  // cheb3: SZ1t = ZSt @ S^T -> SZ1t + AgU[96..159]
  {
    ChebArgs a;
    for (int m = 0; m < 3; ++m) {
      a.S16[m] = S16 + (size_t)m * 1048576; a.A[m] = ZSt + (size_t)m * 524288;
      a.Res[m] = nullptr; a.Yt[m] = SZ1t + (size_t)m * 524288;
      a.AgA[m] = AgU + (size_t)m * 2048000; a.AgX[m] = nullptr;
    }
    cheb_v8<<<dim3(16, 8, 3), 256, 0, stream>>>(a, 64, 96, 1.f, 0.f, 2);
  }
  // cheb4: SZ2t = 2*SZ1t @ S^T - ZSt -> AgU[176..239]
  {
    ChebArgs a;
    for (int m = 0; m < 3; ++m) {
      a.S16[m] = S16 + (size_t)m * 1048576; a.A[m] = SZ1t + (size_t)m * 524288;
      a.Res[m] = ZSt + (size_t)m * 524288; a.Yt[m] = nullptr;
      a.AgA[m] = AgU + (size_t)m * 2048000; a.AgX[m] = nullptr;
    }
    cheb_v8<<<dim3(16, 8, 3), 256, 0, stream>>>(a, 64, 176, 2.f, -1.f, 1);
  }
  // update meta: reads AgU; writes out
  {
    MetaArgs a;
    a.Ag = AgU; a.Bt = BtU; a.ewG = ewG; a.Bias = BiU;
    a.ZSt = ZSt; a.AgU = AgU; a.Rb = Rb; a.out = out;
    for (int m = 0; m < 3; ++m) a.state[m] = st[m];
    meta9<<<dim3(1, 125, 3), 256, 0, stream>>>(a, 0, 64);
  }
}